// Round 9
// baseline (306.061 us; speedup 1.0000x reference)
//
#include <hip/hip_runtime.h>
#include <hip/hip_bf16.h>

#define TSTEPS 60

typedef __attribute__((ext_vector_type(8))) short bf16x8;
typedef __attribute__((ext_vector_type(16))) float f32x16;

// Setup-only scalar conversion.
__device__ __forceinline__ short f2bf(float f) {
    return __builtin_bit_cast(short, __float2bfloat16(f));
}
// Hot-path pack: two f32 -> u32 of 2 bf16 (round-to-nearest, ties away).
// Proven in R6; do NOT replace with v_cvt_pk asm (R5 blowup).
__device__ __forceinline__ unsigned pack2_bf16(float a, float b) {
    unsigned ua = __builtin_bit_cast(unsigned, a) + 0x8000u;
    unsigned ub = __builtin_bit_cast(unsigned, b) + 0x8000u;
    return (ua >> 16) | (ub & 0xFFFF0000u);
}

// One wave = 32 samples via 32x32x16 MFMA. NO LDS h1 round-trip: the D->B
// fragment relayout is done in-register with v_permlane32_swap_b32.
//   L1: h1(64x32) = relu( [W1^T | b1](64x5) @ [x;1](5x32) )           -- 2 MFMA
//   L2: h2(64x32) = [W2^T | b2](64x65) @ [h1;1](65x32)                -- 10 MFMA
//   L3: delta = relu(h2).W3 + b3  (VALU dot, one shfl_xor(32) reduce)
// Frags: A row=lane&31, k=8*(lane>>5)+j ; D col=lane&31, row=(reg&3)+8*(reg>>2)+4*(lane>>5).
//
// permlane32_swap semantics (gfx950): swap(a,b) -> r0 = {a[0:31], b[0:31]},
// r1 = {a[32:63], b[32:63]}. With u[m][q] = pack(rows 32m+8q+4*half+{0,1})
// and B-tile kt needing rows 16kt+8*half+j: r0 of swap(u[m][q0],u[m][q0+1])
// is B-word0 for ALL lanes, r1 is B-word2 (v pair gives words 1,3).
__global__ __launch_bounds__(256)
void ffn_mfma32(const float* __restrict__ feat,
                const float* __restrict__ W1, const float* __restrict__ b1,
                const float* __restrict__ W2, const float* __restrict__ b2,
                const float* __restrict__ W3, const float* __restrict__ b3,
                float* __restrict__ out, int N) {
    __shared__ float dlt[4][32 * 61]; // per-wave output staging, stride 61 = conflict-free

    const int lane = threadIdx.x & 63;
    const int wave = threadIdx.x >> 6;
    const int col  = lane & 31;   // sample column
    const int half = lane >> 5;   // k-group half
    const int nbase = blockIdx.x * 128 + wave * 32;
    if (nbase >= N) return;       // wave-uniform: all 64 lanes stay active

    const unsigned hmask = half ? 0u : 0xFFFFFFFFu;

    // ---- loop-invariant fragments (same as R8-proven) ----
    bf16x8 a1[2];
#pragma unroll
    for (int m = 0; m < 2; ++m) {
        bf16x8 v = {0,0,0,0,0,0,0,0};
        if (half == 0) {
            const int row = m*32 + col;
#pragma unroll
            for (int j = 0; j < 4; ++j) v[j] = f2bf(W1[j*64 + row]);
            v[4] = f2bf(b1[row]);
        }
        a1[m] = v;
    }
    bf16x8 a2[2][5];
#pragma unroll
    for (int m = 0; m < 2; ++m) {
        const int row = m*32 + col;
#pragma unroll
        for (int kt = 0; kt < 4; ++kt) {
            bf16x8 v;
#pragma unroll
            for (int j = 0; j < 8; ++j)
                v[j] = f2bf(W2[(16*kt + 8*half + j)*64 + row]);
            a2[m][kt] = v;
        }
        bf16x8 v = {0,0,0,0,0,0,0,0};
        if (half == 0) v[0] = f2bf(b2[row]);
        a2[m][4] = v;
    }
    float w3f[2][16];
#pragma unroll
    for (int m = 0; m < 2; ++m)
#pragma unroll
        for (int r = 0; r < 16; ++r)
            w3f[m][r] = W3[m*32 + (r&3) + 8*(r>>2) + 4*half];
    const float b3v = b3[0];

    // Ones B-frag for L2's bias K-tile.
    uint4 onesu; onesu.x = 0x3F80u & hmask; onesu.y = 0u; onesu.z = 0u; onesu.w = 0u;
    const bf16x8 hb4 = __builtin_bit_cast(bf16x8, onesu);

    f32x16 zc;
#pragma unroll
    for (int r = 0; r < 16; ++r) zc[r] = 0.0f;

    const float* fp = feat + (size_t)(nbase + col) * (TSTEPS * 3);
    float* dl = dlt[wave];
    float f0 = fp[0], f1 = fp[1], f2v = fp[2];
    float delta = 0.0f;

#pragma unroll 2
    for (int t = 0; t < TSTEPS; ++t) {
        const int tn = (t + 1 < TSTEPS) ? t + 1 : t;   // clamped prefetch (no OOB)
        const float nf0 = fp[tn*3+0], nf1 = fp[tn*3+1], nf2 = fp[tn*3+2];

        // x-frag: k rows [f0,f1,f2,delta,1,0...]; half==1 lanes all zero.
        uint4 xu;
        xu.x = pack2_bf16(f0, f1) & hmask;
        xu.y = pack2_bf16(f2v, delta) & hmask;
        xu.z = 0x3F80u & hmask;
        xu.w = 0u;
        const bf16x8 xb = __builtin_bit_cast(bf16x8, xu);

        // L1 (bias folded): h1 = relu(W1ext @ xext)
        f32x16 h1a[2];
        h1a[0] = __builtin_amdgcn_mfma_f32_32x32x16_bf16(a1[0], xb, zc, 0, 0, 0);
        h1a[1] = __builtin_amdgcn_mfma_f32_32x32x16_bf16(a1[1], xb, zc, 0, 0, 0);

        // relu + pack: u/v[m][q] hold rows 32m+8q+4*half+{0,1}/{2,3} of column col.
        unsigned pu[2][4], pv[2][4];
#pragma unroll
        for (int m = 0; m < 2; ++m)
#pragma unroll
            for (int q = 0; q < 4; ++q) {
                pu[m][q] = pack2_bf16(fmaxf(h1a[m][4*q+0], 0.f), fmaxf(h1a[m][4*q+1], 0.f));
                pv[m][q] = pack2_bf16(fmaxf(h1a[m][4*q+2], 0.f), fmaxf(h1a[m][4*q+3], 0.f));
            }

        // In-register D->B relayout: 2 permlane32_swap per K-tile.
        bf16x8 hbf[4];
#pragma unroll
        for (int kt = 0; kt < 4; ++kt) {
            const int m = kt >> 1, q0 = (kt & 1) * 2;
            auto s0 = __builtin_amdgcn_permlane32_swap(pu[m][q0], pu[m][q0+1], false, false);
            auto s1 = __builtin_amdgcn_permlane32_swap(pv[m][q0], pv[m][q0+1], false, false);
            uint4 w;
            w.x = s0[0];  // rows 16kt+8h+{0,1}
            w.y = s1[0];  // rows 16kt+8h+{2,3}
            w.z = s0[1];  // rows 16kt+8h+{4,5}
            w.w = s1[1];  // rows 16kt+8h+{6,7}
            hbf[kt] = __builtin_bit_cast(bf16x8, w);
        }

        // L2 (bias folded): bias MFMA first -- constant operands, issues while
        // the swaps complete, keeping it off the dependence-critical path.
        f32x16 acc[2];
#pragma unroll
        for (int m = 0; m < 2; ++m) {
            f32x16 a = __builtin_amdgcn_mfma_f32_32x32x16_bf16(a2[m][4], hb4, zc, 0, 0, 0);
            a = __builtin_amdgcn_mfma_f32_32x32x16_bf16(a2[m][0], hbf[0], a, 0, 0, 0);
            a = __builtin_amdgcn_mfma_f32_32x32x16_bf16(a2[m][1], hbf[1], a, 0, 0, 0);
            a = __builtin_amdgcn_mfma_f32_32x32x16_bf16(a2[m][2], hbf[2], a, 0, 0, 0);
            a = __builtin_amdgcn_mfma_f32_32x32x16_bf16(a2[m][3], hbf[3], a, 0, 0, 0);
            acc[m] = a;
        }

        // L3 dot: 4 independent chains; one shfl_xor(32) completes the 64-row sum.
        float p0 = 0.f, p1 = 0.f, p2 = 0.f, p3 = 0.f;
#pragma unroll
        for (int m = 0; m < 2; ++m)
#pragma unroll
            for (int q = 0; q < 4; ++q) {
                p0 = fmaf(fmaxf(acc[m][4*q+0], 0.f), w3f[m][4*q+0], p0);
                p1 = fmaf(fmaxf(acc[m][4*q+1], 0.f), w3f[m][4*q+1], p1);
                p2 = fmaf(fmaxf(acc[m][4*q+2], 0.f), w3f[m][4*q+2], p2);
                p3 = fmaf(fmaxf(acc[m][4*q+3], 0.f), w3f[m][4*q+3], p3);
            }
        float p = (p0 + p1) + (p2 + p3);
        p += __shfl_xor(p, 32, 64);
        delta = p + b3v;

        if (half == 0) dl[col*61 + t] = delta;
        f0 = nf0; f1 = nf1; f2v = nf2;
    }

    // Coalesced flush: out[nbase*60 + i], i = col*60 + t ; LDS idx = col*61+t = i + i/60.
    float* ob = out + (size_t)nbase * TSTEPS;
#pragma unroll 1
    for (int i = lane; i < 32 * TSTEPS; i += 64) {
        const int cc = i / TSTEPS;
        ob[i] = dl[i + cc];
    }
}

extern "C" void kernel_launch(void* const* d_in, const int* in_sizes, int n_in,
                              void* d_out, int out_size, void* d_ws, size_t ws_size,
                              hipStream_t stream) {
    const float* feat = (const float*)d_in[0];
    const float* W1   = (const float*)d_in[1];
    const float* b1   = (const float*)d_in[2];
    const float* W2   = (const float*)d_in[3];
    const float* b2   = (const float*)d_in[4];
    const float* W3   = (const float*)d_in[5];
    const float* b3   = (const float*)d_in[6];
    float* out = (float*)d_out;

    const int N = in_sizes[0] / (TSTEPS * 3);
    const int block = 256;                  // 4 waves x 32 samples = 128 samples/block
    const int grid = (N + 127) / 128;
    ffn_mfma32<<<grid, block, 0, stream>>>(feat, W1, b1, W2, b2, W3, b3, out, N);
}

// Round 11
// 272.577 us; speedup vs baseline: 1.1228x; 1.1228x over previous
//
#include <hip/hip_runtime.h>
#include <hip/hip_bf16.h>

#define TSTEPS 60

typedef __attribute__((ext_vector_type(8))) short bf16x8;
typedef __attribute__((ext_vector_type(16))) float f32x16;

// Setup-only scalar conversions.
__device__ __forceinline__ short f2bf(float f) {
    return __builtin_bit_cast(short, __float2bfloat16(f));
}
__device__ __forceinline__ float bf2f(short s) {
    return __builtin_bit_cast(float, (unsigned)(unsigned short)s << 16);
}
// Hot-path pack: two f32 -> u32 of 2 bf16 (round-to-nearest, ties away).
// Proven R6; do NOT replace with v_cvt_pk asm (R5 blowup).
__device__ __forceinline__ unsigned pack2_bf16(float a, float b) {
    unsigned ua = __builtin_bit_cast(unsigned, a) + 0x8000u;
    unsigned ub = __builtin_bit_cast(unsigned, b) + 0x8000u;
    return (ua >> 16) | (ub & 0xFFFF0000u);
}

// One wave = 32 samples via 32x32x16 MFMA; chain-minimized recurrence.
//   P_t   = [W1^T|b1] @ [f_t;0;1]          (MFMA, pipelined one step AHEAD, off-chain)
//   h1_t  = relu(P_t + w1d * delta_{t-1})  (VALU inject -- the only L1 work on the chain)
//   h2_t  = [W2^T|b2] @ [h1;1]             (bias MFMA first = C-init; 4 dependent MFMAs)
//   delta = relu(h2).W3 + b3               (VALU dot + shfl_xor(32) cross-half sum)
// Frags: A row=lane&31, k=8*(lane>>5)+j ; D col=lane&31, row=(reg&3)+8*(reg>>2)+4*(lane>>5).
//
// HAZARD (R10 lesson): permlane32_swap is a REGISTER EXCHANGE. With identical
// operands (swap(p,p)) the compiler may allocate ONE register for both ->
// the exchange degenerates to a half-swap and the "reduce" returns 2*p[i^32].
// Only use permlane32_swap with two DISTINCT values (as in the relayout below);
// for self-reduction use __shfl_xor (proven R3-R9).
__global__ __launch_bounds__(256, 2)
void ffn_mfma32(const float* __restrict__ feat,
                const float* __restrict__ W1, const float* __restrict__ b1,
                const float* __restrict__ W2, const float* __restrict__ b2,
                const float* __restrict__ W3, const float* __restrict__ b3,
                float* __restrict__ out, int N) {
    __shared__ float dlt[4][32 * 61]; // per-wave output staging, stride 61 = conflict-free

    const int lane = threadIdx.x & 63;
    const int wave = threadIdx.x >> 6;
    const int col  = lane & 31;   // sample column
    const int half = lane >> 5;   // k-group half
    const int nbase = blockIdx.x * 128 + wave * 32;
    if (nbase >= N) return;       // wave-uniform

    // ---- loop-invariant fragments ----
    // L1 A: k<3 -> W1[k][row], k==3 -> W1[3][row] (times 0 in x), k==4 -> b1[row].
    bf16x8 a1[2];
#pragma unroll
    for (int m = 0; m < 2; ++m) {
        bf16x8 v = {0,0,0,0,0,0,0,0};
        if (half == 0) {
            const int row = m*32 + col;
#pragma unroll
            for (int j = 0; j < 4; ++j) v[j] = f2bf(W1[j*64 + row]);
            v[4] = f2bf(b1[row]);
        }
        a1[m] = v;
    }
    // L2 A: kt 0..3 = W2^T, kt 4 = bias column (k=64 -> b2[row]).
    bf16x8 a2[2][5];
#pragma unroll
    for (int m = 0; m < 2; ++m) {
        const int row = m*32 + col;
#pragma unroll
        for (int kt = 0; kt < 4; ++kt) {
            bf16x8 v;
#pragma unroll
            for (int j = 0; j < 8; ++j)
                v[j] = f2bf(W2[(16*kt + 8*half + j)*64 + row]);
            a2[m][kt] = v;
        }
        bf16x8 v = {0,0,0,0,0,0,0,0};
        if (half == 0) v[0] = f2bf(b2[row]);
        a2[m][4] = v;
    }
    // W3 and W1-delta-row (w1d) in D layout, f32.
    float w3f[2][16], w1d[2][16];
#pragma unroll
    for (int m = 0; m < 2; ++m)
#pragma unroll
        for (int r = 0; r < 16; ++r) {
            const int row = m*32 + (r&3) + 8*(r>>2) + 4*half;
            w3f[m][r] = W3[row];
            w1d[m][r] = bf2f(f2bf(W1[3*64 + row]));  // same quantization as MFMA path
        }
    const float b3v = b3[0];

    // Ones B-frag for L2's bias K-tile (half-1 lanes' rows hit zero A coeffs).
    uint4 onesu; onesu.x = 0x3F80u; onesu.y = 0u; onesu.z = 0u; onesu.w = 0u;
    const bf16x8 hb4 = __builtin_bit_cast(bf16x8, onesu);

    f32x16 zc;
#pragma unroll
    for (int r = 0; r < 16; ++r) zc[r] = 0.0f;

    const float* fp = feat + (size_t)(nbase + col) * (TSTEPS * 3);
    float* dl = dlt[wave];

    // Prologue: P for t=0 (delta slot 0, bias via ones row).
    f32x16 PA0, PA1, PB0, PB1;
    {
        uint4 xu;
        xu.x = pack2_bf16(fp[0], fp[1]);
        xu.y = pack2_bf16(fp[2], 0.f);
        xu.z = 0x3F80u; xu.w = 0u;
        const bf16x8 xb = __builtin_bit_cast(bf16x8, xu);
        PA0 = __builtin_amdgcn_mfma_f32_32x32x16_bf16(a1[0], xb, zc, 0, 0, 0);
        PA1 = __builtin_amdgcn_mfma_f32_32x32x16_bf16(a1[1], xb, zc, 0, 0, 0);
    }
    float delta = 0.0f;

    // One step: consumes Pc (current pre-activation), produces Pn (next step's).
    auto stepfn = [&](int t, const f32x16& Pc0, const f32x16& Pc1,
                      f32x16& Pn0, f32x16& Pn1) {
        const int tn = (t + 1 < TSTEPS) ? t + 1 : t;   // clamped prefetch
        const float nf0 = fp[tn*3+0], nf1 = fp[tn*3+1], nf2 = fp[tn*3+2];

        // Off-chain: bias MFMAs (invariant operands) issue immediately = C-init.
        f32x16 acc0 = __builtin_amdgcn_mfma_f32_32x32x16_bf16(a2[0][4], hb4, zc, 0, 0, 0);
        f32x16 acc1 = __builtin_amdgcn_mfma_f32_32x32x16_bf16(a2[1][4], hb4, zc, 0, 0, 0);

        // Critical chain: delta injection + relu + pack (rows 8q+4h+{0,1}/{2,3}).
        unsigned pu[2][4], pv[2][4];
#pragma unroll
        for (int m = 0; m < 2; ++m) {
            const f32x16& P = m ? Pc1 : Pc0;
#pragma unroll
            for (int q = 0; q < 4; ++q) {
                const float r0 = fmaxf(fmaf(w1d[m][4*q+0], delta, P[4*q+0]), 0.f);
                const float r1 = fmaxf(fmaf(w1d[m][4*q+1], delta, P[4*q+1]), 0.f);
                const float r2 = fmaxf(fmaf(w1d[m][4*q+2], delta, P[4*q+2]), 0.f);
                const float r3 = fmaxf(fmaf(w1d[m][4*q+3], delta, P[4*q+3]), 0.f);
                pu[m][q] = pack2_bf16(r0, r1);
                pv[m][q] = pack2_bf16(r2, r3);
            }
        }

        // In-register D->B relayout: 2 permlane32_swap per K-tile (distinct
        // operands -> safe; R9-proven).
        bf16x8 hbf[4];
#pragma unroll
        for (int kt = 0; kt < 4; ++kt) {
            const int m = kt >> 1, q0 = (kt & 1) * 2;
            auto s0 = __builtin_amdgcn_permlane32_swap(pu[m][q0], pu[m][q0+1], false, false);
            auto s1 = __builtin_amdgcn_permlane32_swap(pv[m][q0], pv[m][q0+1], false, false);
            uint4 w;
            w.x = s0[0]; w.y = s1[0]; w.z = s0[1]; w.w = s1[1];
            hbf[kt] = __builtin_bit_cast(bf16x8, w);
        }

        // L2: 4 dependent MFMAs per half (bias already in C).
        acc0 = __builtin_amdgcn_mfma_f32_32x32x16_bf16(a2[0][0], hbf[0], acc0, 0, 0, 0);
        acc1 = __builtin_amdgcn_mfma_f32_32x32x16_bf16(a2[1][0], hbf[0], acc1, 0, 0, 0);
        acc0 = __builtin_amdgcn_mfma_f32_32x32x16_bf16(a2[0][1], hbf[1], acc0, 0, 0, 0);
        acc1 = __builtin_amdgcn_mfma_f32_32x32x16_bf16(a2[1][1], hbf[1], acc1, 0, 0, 0);
        acc0 = __builtin_amdgcn_mfma_f32_32x32x16_bf16(a2[0][2], hbf[2], acc0, 0, 0, 0);
        acc1 = __builtin_amdgcn_mfma_f32_32x32x16_bf16(a2[1][2], hbf[2], acc1, 0, 0, 0);
        acc0 = __builtin_amdgcn_mfma_f32_32x32x16_bf16(a2[0][3], hbf[3], acc0, 0, 0, 0);
        acc1 = __builtin_amdgcn_mfma_f32_32x32x16_bf16(a2[1][3], hbf[3], acc1, 0, 0, 0);

        // Off-chain: next step's delta-independent L1 (software pipeline).
        {
            uint4 xu;
            xu.x = pack2_bf16(nf0, nf1);
            xu.y = pack2_bf16(nf2, 0.f);
            xu.z = 0x3F80u; xu.w = 0u;
            const bf16x8 xb = __builtin_bit_cast(bf16x8, xu);
            Pn0 = __builtin_amdgcn_mfma_f32_32x32x16_bf16(a1[0], xb, zc, 0, 0, 0);
            Pn1 = __builtin_amdgcn_mfma_f32_32x32x16_bf16(a1[1], xb, zc, 0, 0, 0);
        }

        // L3 dot: 4 independent chains over both halves' accumulators.
        float p0 = 0.f, p1 = 0.f, p2 = 0.f, p3 = 0.f;
#pragma unroll
        for (int q = 0; q < 4; ++q) {
            p0 = fmaf(fmaxf(acc0[4*q+0], 0.f), w3f[0][4*q+0], p0);
            p1 = fmaf(fmaxf(acc0[4*q+1], 0.f), w3f[0][4*q+1], p1);
            p2 = fmaf(fmaxf(acc0[4*q+2], 0.f), w3f[0][4*q+2], p2);
            p3 = fmaf(fmaxf(acc0[4*q+3], 0.f), w3f[0][4*q+3], p3);
            p0 = fmaf(fmaxf(acc1[4*q+0], 0.f), w3f[1][4*q+0], p0);
            p1 = fmaf(fmaxf(acc1[4*q+1], 0.f), w3f[1][4*q+1], p1);
            p2 = fmaf(fmaxf(acc1[4*q+2], 0.f), w3f[1][4*q+2], p2);
            p3 = fmaf(fmaxf(acc1[4*q+3], 0.f), w3f[1][4*q+3], p3);
        }
        float p = (p0 + p1) + (p2 + p3);
        p += __shfl_xor(p, 32, 64);   // cross-half sum (R9-proven; see hazard note)
        delta = p + b3v;

        if (half == 0) dl[col*61 + t] = delta;
    };

    // Ping-pong P buffers: no register copies between steps.
#pragma unroll 1
    for (int t = 0; t < TSTEPS; t += 2) {
        stepfn(t,     PA0, PA1, PB0, PB1);
        stepfn(t + 1, PB0, PB1, PA0, PA1);
    }

    // Coalesced flush: out[nbase*60 + i], i = col*60 + t ; LDS idx = i + i/60.
    float* ob = out + (size_t)nbase * TSTEPS;
#pragma unroll 1
    for (int i = lane; i < 32 * TSTEPS; i += 64) {
        const int cc = i / TSTEPS;
        ob[i] = dl[i + cc];
    }
}

extern "C" void kernel_launch(void* const* d_in, const int* in_sizes, int n_in,
                              void* d_out, int out_size, void* d_ws, size_t ws_size,
                              hipStream_t stream) {
    const float* feat = (const float*)d_in[0];
    const float* W1   = (const float*)d_in[1];
    const float* b1   = (const float*)d_in[2];
    const float* W2   = (const float*)d_in[3];
    const float* b2   = (const float*)d_in[4];
    const float* W3   = (const float*)d_in[5];
    const float* b3   = (const float*)d_in[6];
    float* out = (float*)d_out;

    const int N = in_sizes[0] / (TSTEPS * 3);
    const int block = 256;                  // 4 waves x 32 samples = 128 samples/block
    const int grid = (N + 127) / 128;
    ffn_mfma32<<<grid, block, 0, stream>>>(feat, W1, b1, W2, b2, W3, b3, out, N);
}

// Round 12
// 271.179 us; speedup vs baseline: 1.1286x; 1.0052x over previous
//
#include <hip/hip_runtime.h>
#include <hip/hip_bf16.h>

#define TSTEPS 60

typedef __attribute__((ext_vector_type(8))) short bf16x8;
typedef __attribute__((ext_vector_type(16))) float f32x16;
typedef __attribute__((ext_vector_type(2))) float f32x2;

// Setup-only scalar conversions.
__device__ __forceinline__ short f2bf(float f) {
    return __builtin_bit_cast(short, __float2bfloat16(f));
}
__device__ __forceinline__ float bf2f(short s) {
    return __builtin_bit_cast(float, (unsigned)(unsigned short)s << 16);
}
// Hot-path pack: two f32 -> u32 of 2 bf16 (round-to-nearest, ties away).
// Merge via v_perm_b32 (1 instr instead of shift+and+or). Bit-identical to
// the R6-proven version. Do NOT use v_cvt_pk asm (R5 blowup).
__device__ __forceinline__ unsigned pack2_bf16(float a, float b) {
    unsigned ua = __builtin_bit_cast(unsigned, a) + 0x8000u;
    unsigned ub = __builtin_bit_cast(unsigned, b) + 0x8000u;
    // dst bytes (LE) = [ua.b2, ua.b3, ub.b2, ub.b3]  == (ua>>16)|(ub&0xFFFF0000)
    return __builtin_amdgcn_perm(ub, ua, 0x07060302u);
}
__device__ __forceinline__ unsigned pack2_bf16_v(f32x2 v) {
    return pack2_bf16(v[0], v[1]);
}

// One wave = 32 samples via 32x32x16 MFMA; chain-minimized recurrence.
//   P_t   = [W1^T|b1] @ [f_t;0;1]          (MFMA, pipelined one step AHEAD, off-chain)
//   h1_t  = relu(P_t + w1d * delta_{t-1})  (packed-f32 VALU inject)
//   h2_t  = [W2^T|b2] @ [h1;1]             (bias MFMA first = C-init; 4 dependent MFMAs)
//   delta = relu(h2).W3 + b3               (packed-f32 dot + shfl_xor(32))
// Frags: A row=lane&31, k=8*(lane>>5)+j ; D col=lane&31, row=(reg&3)+8*(reg>>2)+4*(lane>>5).
//
// HAZARD (R10): permlane32_swap is a REGISTER EXCHANGE -- identical operands
// degenerate (compiler may alias them to one register). Only use with two
// DISTINCT values; self-reduction uses __shfl_xor.
__global__ __launch_bounds__(256, 2)
void ffn_mfma32(const float* __restrict__ feat,
                const float* __restrict__ W1, const float* __restrict__ b1,
                const float* __restrict__ W2, const float* __restrict__ b2,
                const float* __restrict__ W3, const float* __restrict__ b3,
                float* __restrict__ out, int N) {
    __shared__ float dlt[4][32 * 61]; // per-wave output staging, stride 61 = conflict-free

    const int lane = threadIdx.x & 63;
    const int wave = threadIdx.x >> 6;
    const int col  = lane & 31;   // sample column
    const int half = lane >> 5;   // k-group half
    const int nbase = blockIdx.x * 128 + wave * 32;
    if (nbase >= N) return;       // wave-uniform

    // ---- loop-invariant fragments ----
    bf16x8 a1[2];
#pragma unroll
    for (int m = 0; m < 2; ++m) {
        bf16x8 v = {0,0,0,0,0,0,0,0};
        if (half == 0) {
            const int row = m*32 + col;
#pragma unroll
            for (int j = 0; j < 4; ++j) v[j] = f2bf(W1[j*64 + row]);
            v[4] = f2bf(b1[row]);
        }
        a1[m] = v;
    }
    bf16x8 a2[2][5];
#pragma unroll
    for (int m = 0; m < 2; ++m) {
        const int row = m*32 + col;
#pragma unroll
        for (int kt = 0; kt < 4; ++kt) {
            bf16x8 v;
#pragma unroll
            for (int j = 0; j < 8; ++j)
                v[j] = f2bf(W2[(16*kt + 8*half + j)*64 + row]);
            a2[m][kt] = v;
        }
        bf16x8 v = {0,0,0,0,0,0,0,0};
        if (half == 0) v[0] = f2bf(b2[row]);
        a2[m][4] = v;
    }
    // W3 and W1-delta-row in D layout, stored as f32x2 pairs (reg layout identical
    // to R11's scalar arrays; enables v_pk_fma_f32 formation).
    f32x2 w3f[2][8], w1d[2][8];
#pragma unroll
    for (int m = 0; m < 2; ++m)
#pragma unroll
        for (int r = 0; r < 8; ++r) {
            const int r0 = 2*r, r1 = 2*r + 1;
            const int row0 = m*32 + (r0&3) + 8*(r0>>2) + 4*half;
            const int row1 = m*32 + (r1&3) + 8*(r1>>2) + 4*half;
            w3f[m][r] = (f32x2){ W3[row0], W3[row1] };
            w1d[m][r] = (f32x2){ bf2f(f2bf(W1[3*64 + row0])), bf2f(f2bf(W1[3*64 + row1])) };
        }
    const float b3v = b3[0];

    // Ones B-frag for L2's bias K-tile (half-1 lanes' rows hit zero A coeffs).
    uint4 onesu; onesu.x = 0x3F80u; onesu.y = 0u; onesu.z = 0u; onesu.w = 0u;
    const bf16x8 hb4 = __builtin_bit_cast(bf16x8, onesu);

    f32x16 zc;
#pragma unroll
    for (int r = 0; r < 16; ++r) zc[r] = 0.0f;
    const f32x2 z2 = {0.f, 0.f};

    const float* fp = feat + (size_t)(nbase + col) * (TSTEPS * 3);
    float* dl = dlt[wave];

    // Prologue: P for t=0 (delta slot 0, bias via ones row).
    f32x16 PA0, PA1, PB0, PB1;
    {
        uint4 xu;
        xu.x = pack2_bf16(fp[0], fp[1]);
        xu.y = pack2_bf16(fp[2], 0.f);
        xu.z = 0x3F80u; xu.w = 0u;
        const bf16x8 xb = __builtin_bit_cast(bf16x8, xu);
        PA0 = __builtin_amdgcn_mfma_f32_32x32x16_bf16(a1[0], xb, zc, 0, 0, 0);
        PA1 = __builtin_amdgcn_mfma_f32_32x32x16_bf16(a1[1], xb, zc, 0, 0, 0);
    }
    float delta = 0.0f;

    auto stepfn = [&](int t, const f32x16& Pc0, const f32x16& Pc1,
                      f32x16& Pn0, f32x16& Pn1) {
        const int tn = (t + 1 < TSTEPS) ? t + 1 : t;   // clamped prefetch
        const float nf0 = fp[tn*3+0], nf1 = fp[tn*3+1], nf2 = fp[tn*3+2];

        // Off-chain: bias MFMAs (invariant operands) = C-init.
        f32x16 acc0 = __builtin_amdgcn_mfma_f32_32x32x16_bf16(a2[0][4], hb4, zc, 0, 0, 0);
        f32x16 acc1 = __builtin_amdgcn_mfma_f32_32x32x16_bf16(a2[1][4], hb4, zc, 0, 0, 0);

        // Critical chain: packed-f32 delta injection + relu + perm-pack.
        const f32x2 dv = {delta, delta};
        unsigned pu[2][4], pv[2][4];
#pragma unroll
        for (int m = 0; m < 2; ++m) {
            const f32x16& P = m ? Pc1 : Pc0;
#pragma unroll
            for (int q = 0; q < 4; ++q) {
                f32x2 Plo = __builtin_shufflevector(P, P, -1, -1);
                f32x2 Phi = __builtin_shufflevector(P, P, -1, -1);
                // (shufflevector needs constant indices; expand manually)
                Plo[0] = P[4*q+0]; Plo[1] = P[4*q+1];
                Phi[0] = P[4*q+2]; Phi[1] = P[4*q+3];
                f32x2 rlo = __builtin_elementwise_max(
                    __builtin_elementwise_fma(w1d[m][2*q+0], dv, Plo), z2);
                f32x2 rhi = __builtin_elementwise_max(
                    __builtin_elementwise_fma(w1d[m][2*q+1], dv, Phi), z2);
                pu[m][q] = pack2_bf16_v(rlo);
                pv[m][q] = pack2_bf16_v(rhi);
            }
        }

        // In-register D->B relayout: 2 permlane32_swap per K-tile (distinct operands).
        bf16x8 hbf[4];
#pragma unroll
        for (int kt = 0; kt < 4; ++kt) {
            const int m = kt >> 1, q0 = (kt & 1) * 2;
            auto s0 = __builtin_amdgcn_permlane32_swap(pu[m][q0], pu[m][q0+1], false, false);
            auto s1 = __builtin_amdgcn_permlane32_swap(pv[m][q0], pv[m][q0+1], false, false);
            uint4 w;
            w.x = s0[0]; w.y = s1[0]; w.z = s0[1]; w.w = s1[1];
            hbf[kt] = __builtin_bit_cast(bf16x8, w);
        }

        // L2: 4 dependent MFMAs per half (bias already in C).
        acc0 = __builtin_amdgcn_mfma_f32_32x32x16_bf16(a2[0][0], hbf[0], acc0, 0, 0, 0);
        acc1 = __builtin_amdgcn_mfma_f32_32x32x16_bf16(a2[1][0], hbf[0], acc1, 0, 0, 0);
        acc0 = __builtin_amdgcn_mfma_f32_32x32x16_bf16(a2[0][1], hbf[1], acc0, 0, 0, 0);
        acc1 = __builtin_amdgcn_mfma_f32_32x32x16_bf16(a2[1][1], hbf[1], acc1, 0, 0, 0);
        acc0 = __builtin_amdgcn_mfma_f32_32x32x16_bf16(a2[0][2], hbf[2], acc0, 0, 0, 0);
        acc1 = __builtin_amdgcn_mfma_f32_32x32x16_bf16(a2[1][2], hbf[2], acc1, 0, 0, 0);
        acc0 = __builtin_amdgcn_mfma_f32_32x32x16_bf16(a2[0][3], hbf[3], acc0, 0, 0, 0);
        acc1 = __builtin_amdgcn_mfma_f32_32x32x16_bf16(a2[1][3], hbf[3], acc1, 0, 0, 0);

        // Off-chain: next step's delta-independent L1 (software pipeline).
        {
            uint4 xu;
            xu.x = pack2_bf16(nf0, nf1);
            xu.y = pack2_bf16(nf2, 0.f);
            xu.z = 0x3F80u; xu.w = 0u;
            const bf16x8 xb = __builtin_bit_cast(bf16x8, xu);
            Pn0 = __builtin_amdgcn_mfma_f32_32x32x16_bf16(a1[0], xb, zc, 0, 0, 0);
            Pn1 = __builtin_amdgcn_mfma_f32_32x32x16_bf16(a1[1], xb, zc, 0, 0, 0);
        }

        // L3 dot: packed-f32, same chains/order as R11's p0..p3 (bit-identical).
        f32x2 p01 = z2, p23 = z2;
#pragma unroll
        for (int q = 0; q < 4; ++q) {
            f32x2 a0lo, a0hi, a1lo, a1hi;
            a0lo[0] = acc0[4*q+0]; a0lo[1] = acc0[4*q+1];
            a0hi[0] = acc0[4*q+2]; a0hi[1] = acc0[4*q+3];
            a1lo[0] = acc1[4*q+0]; a1lo[1] = acc1[4*q+1];
            a1hi[0] = acc1[4*q+2]; a1hi[1] = acc1[4*q+3];
            p01 = __builtin_elementwise_fma(__builtin_elementwise_max(a0lo, z2), w3f[0][2*q+0], p01);
            p23 = __builtin_elementwise_fma(__builtin_elementwise_max(a0hi, z2), w3f[0][2*q+1], p23);
            p01 = __builtin_elementwise_fma(__builtin_elementwise_max(a1lo, z2), w3f[1][2*q+0], p01);
            p23 = __builtin_elementwise_fma(__builtin_elementwise_max(a1hi, z2), w3f[1][2*q+1], p23);
        }
        float p = (p01[0] + p01[1]) + (p23[0] + p23[1]);
        p += __shfl_xor(p, 32, 64);   // cross-half sum (see hazard note)
        delta = p + b3v;

        if (half == 0) dl[col*61 + t] = delta;
    };

    // Ping-pong P buffers: no register copies between steps.
#pragma unroll 1
    for (int t = 0; t < TSTEPS; t += 2) {
        stepfn(t,     PA0, PA1, PB0, PB1);
        stepfn(t + 1, PB0, PB1, PA0, PA1);
    }

    // Coalesced flush: out[nbase*60 + i], i = col*60 + t ; LDS idx = i + i/60.
    float* ob = out + (size_t)nbase * TSTEPS;
#pragma unroll 1
    for (int i = lane; i < 32 * TSTEPS; i += 64) {
        const int cc = i / TSTEPS;
        ob[i] = dl[i + cc];
    }
}

extern "C" void kernel_launch(void* const* d_in, const int* in_sizes, int n_in,
                              void* d_out, int out_size, void* d_ws, size_t ws_size,
                              hipStream_t stream) {
    const float* feat = (const float*)d_in[0];
    const float* W1   = (const float*)d_in[1];
    const float* b1   = (const float*)d_in[2];
    const float* W2   = (const float*)d_in[3];
    const float* b2   = (const float*)d_in[4];
    const float* W3   = (const float*)d_in[5];
    const float* b3   = (const float*)d_in[6];
    float* out = (float*)d_out;

    const int N = in_sizes[0] / (TSTEPS * 3);
    const int block = 256;                  // 4 waves x 32 samples = 128 samples/block
    const int grid = (N + 127) / 128;
    ffn_mfma32<<<grid, block, 0, stream>>>(feat, W1, b1, W2, b2, W3, b3, out, N);
}

// Round 14
// 253.118 us; speedup vs baseline: 1.2092x; 1.0714x over previous
//
#include <hip/hip_runtime.h>
#include <hip/hip_bf16.h>

#define TSTEPS 60

typedef __attribute__((ext_vector_type(8))) short bf16x8;
typedef __attribute__((ext_vector_type(16))) float f32x16;
typedef __attribute__((ext_vector_type(2))) float f32x2;

// Setup-only scalar conversions.
__device__ __forceinline__ short f2bf(float f) {
    return __builtin_bit_cast(short, __float2bfloat16(f));
}
__device__ __forceinline__ float bf2f(short s) {
    return __builtin_bit_cast(float, (unsigned)(unsigned short)s << 16);
}
// Hot-path pack: two f32 -> u32 of 2 bf16 (round-to-nearest, ties away).
// Merge via v_perm_b32. Do NOT use v_cvt_pk asm (R5 blowup).
__device__ __forceinline__ unsigned pack2_bf16(float a, float b) {
    unsigned ua = __builtin_bit_cast(unsigned, a) + 0x8000u;
    unsigned ub = __builtin_bit_cast(unsigned, b) + 0x8000u;
    return __builtin_amdgcn_perm(ub, ua, 0x07060302u);
}
__device__ __forceinline__ unsigned pack2_bf16_v(f32x2 v) {
    return pack2_bf16(v[0], v[1]);
}

// One wave = 32 samples via 32x32x16 MFMA; chain-minimized recurrence.
//   P_t   = [W1^T|b1] @ [f_t;0;1]          (MFMA, pipelined one step AHEAD, off-chain)
//   h1_t  = relu(P_t + w1d * delta_{t-1})  (packed-f32 VALU inject)
//   h2_t  = [W2^T|b2] @ [h1;1]             (4 independent 2-deep MFMA chains + pk-add merge)
//   delta = relu(h2).W3 + b3               (packed dot + shfl_xor(32))
// Frags: A row=lane&31, k=8*(lane>>5)+j ; D col=lane&31, row=(reg&3)+8*(reg>>2)+4*(lane>>5).
//
// HAZARD (R10 + R13, twice-confirmed): permlane32_swap SELF-reduction is
// broken -- swap(p, p) AND swap(p, forced_copy(p)) both return the degenerate
// single-register half-swap (result 2*p[i^32], absmax 0.34375 both times).
// Mechanism unresolved; BANNED. Only use permlane32_swap with two distinct
// VALUES whose two results are both consumed (the relayout below, R9-proven).
// Cross-half self-reduction must use __shfl_xor (proven R3-R12).
__global__ __launch_bounds__(256, 2)
void ffn_mfma32(const float* __restrict__ feat,
                const float* __restrict__ W1, const float* __restrict__ b1,
                const float* __restrict__ W2, const float* __restrict__ b2,
                const float* __restrict__ W3, const float* __restrict__ b3,
                float* __restrict__ out, int N) {
    __shared__ float dlt[4][32 * 61]; // per-wave output staging, stride 61 = conflict-free

    const int lane = threadIdx.x & 63;
    const int wave = threadIdx.x >> 6;
    const int col  = lane & 31;   // sample column
    const int half = lane >> 5;   // k-group half
    const int nbase = blockIdx.x * 128 + wave * 32;
    if (nbase >= N) return;       // wave-uniform

    // ---- loop-invariant fragments ----
    bf16x8 a1[2];
#pragma unroll
    for (int m = 0; m < 2; ++m) {
        bf16x8 v = {0,0,0,0,0,0,0,0};
        if (half == 0) {
            const int row = m*32 + col;
#pragma unroll
            for (int j = 0; j < 4; ++j) v[j] = f2bf(W1[j*64 + row]);
            v[4] = f2bf(b1[row]);
        }
        a1[m] = v;
    }
    bf16x8 a2[2][5];
#pragma unroll
    for (int m = 0; m < 2; ++m) {
        const int row = m*32 + col;
#pragma unroll
        for (int kt = 0; kt < 4; ++kt) {
            bf16x8 v;
#pragma unroll
            for (int j = 0; j < 8; ++j)
                v[j] = f2bf(W2[(16*kt + 8*half + j)*64 + row]);
            a2[m][kt] = v;
        }
        bf16x8 v = {0,0,0,0,0,0,0,0};
        if (half == 0) v[0] = f2bf(b2[row]);
        a2[m][4] = v;
    }
    // W3 and W1-delta-row in D layout, f32x2 pairs (v_pk_fma_f32 formation).
    f32x2 w3f[2][8], w1d[2][8];
#pragma unroll
    for (int m = 0; m < 2; ++m)
#pragma unroll
        for (int r = 0; r < 8; ++r) {
            const int r0 = 2*r, r1 = 2*r + 1;
            const int row0 = m*32 + (r0&3) + 8*(r0>>2) + 4*half;
            const int row1 = m*32 + (r1&3) + 8*(r1>>2) + 4*half;
            w3f[m][r] = (f32x2){ W3[row0], W3[row1] };
            w1d[m][r] = (f32x2){ bf2f(f2bf(W1[3*64 + row0])), bf2f(f2bf(W1[3*64 + row1])) };
        }
    const float b3v = b3[0];

    // Ones B-frag for L2's bias K-tile (half-1 lanes' rows hit zero A coeffs).
    uint4 onesu; onesu.x = 0x3F80u; onesu.y = 0u; onesu.z = 0u; onesu.w = 0u;
    const bf16x8 hb4 = __builtin_bit_cast(bf16x8, onesu);

    f32x16 zc;
#pragma unroll
    for (int r = 0; r < 16; ++r) zc[r] = 0.0f;
    const f32x2 z2 = {0.f, 0.f};

    const float* fp = feat + (size_t)(nbase + col) * (TSTEPS * 3);
    float* dl = dlt[wave];

    // Prologue: P for t=0 (delta slot 0, bias via ones row).
    f32x16 PA0, PA1, PB0, PB1;
    {
        uint4 xu;
        xu.x = pack2_bf16(fp[0], fp[1]);
        xu.y = pack2_bf16(fp[2], 0.f);
        xu.z = 0x3F80u; xu.w = 0u;
        const bf16x8 xb = __builtin_bit_cast(bf16x8, xu);
        PA0 = __builtin_amdgcn_mfma_f32_32x32x16_bf16(a1[0], xb, zc, 0, 0, 0);
        PA1 = __builtin_amdgcn_mfma_f32_32x32x16_bf16(a1[1], xb, zc, 0, 0, 0);
    }
    float delta = 0.0f;

    auto stepfn = [&](int t, const f32x16& Pc0, const f32x16& Pc1,
                      f32x16& Pn0, f32x16& Pn1) {
        const int tn = (t + 1 < TSTEPS) ? t + 1 : t;   // clamped prefetch
        const float nf0 = fp[tn*3+0], nf1 = fp[tn*3+1], nf2 = fp[tn*3+2];

        // Off-chain: bias MFMAs (invariant operands) = C-init of the 'a' chains.
        f32x16 acc0 = __builtin_amdgcn_mfma_f32_32x32x16_bf16(a2[0][4], hb4, zc, 0, 0, 0);
        f32x16 acc1 = __builtin_amdgcn_mfma_f32_32x32x16_bf16(a2[1][4], hb4, zc, 0, 0, 0);

        // Critical chain: packed-f32 delta injection + relu + perm-pack.
        const f32x2 dv = {delta, delta};
        unsigned pu[2][4], pv[2][4];
#pragma unroll
        for (int m = 0; m < 2; ++m) {
            const f32x16& P = m ? Pc1 : Pc0;
#pragma unroll
            for (int q = 0; q < 4; ++q) {
                f32x2 Plo = { P[4*q+0], P[4*q+1] };
                f32x2 Phi = { P[4*q+2], P[4*q+3] };
                f32x2 rlo = __builtin_elementwise_max(
                    __builtin_elementwise_fma(w1d[m][2*q+0], dv, Plo), z2);
                f32x2 rhi = __builtin_elementwise_max(
                    __builtin_elementwise_fma(w1d[m][2*q+1], dv, Phi), z2);
                pu[m][q] = pack2_bf16_v(rlo);
                pv[m][q] = pack2_bf16_v(rhi);
            }
        }

        // In-register D->B relayout: 2 permlane32_swap per K-tile (distinct
        // values, both results consumed -- the SAFE pattern).
        bf16x8 hbf[4];
#pragma unroll
        for (int kt = 0; kt < 4; ++kt) {
            const int m = kt >> 1, q0 = (kt & 1) * 2;
            auto s0 = __builtin_amdgcn_permlane32_swap(pu[m][q0], pu[m][q0+1], false, false);
            auto s1 = __builtin_amdgcn_permlane32_swap(pv[m][q0], pv[m][q0+1], false, false);
            uint4 w;
            w.x = s0[0]; w.y = s1[0]; w.z = s0[1]; w.w = s1[1];
            hbf[kt] = __builtin_bit_cast(bf16x8, w);
        }

        // L2: 4 INDEPENDENT 2-deep MFMA chains (was: 2 chains of 4 dependent).
        // 'a' chains carry the bias C-init; 'b' chains start from zero and are
        // merged with packed adds. Cuts the hbf->acc critical path from 4 MFMA
        // latencies to 2 + one add.
        __builtin_amdgcn_s_setprio(1);
        f32x16 acc0a = __builtin_amdgcn_mfma_f32_32x32x16_bf16(a2[0][0], hbf[0], acc0, 0, 0, 0);
        f32x16 acc1a = __builtin_amdgcn_mfma_f32_32x32x16_bf16(a2[1][0], hbf[0], acc1, 0, 0, 0);
        f32x16 acc0b = __builtin_amdgcn_mfma_f32_32x32x16_bf16(a2[0][2], hbf[2], zc, 0, 0, 0);
        f32x16 acc1b = __builtin_amdgcn_mfma_f32_32x32x16_bf16(a2[1][2], hbf[2], zc, 0, 0, 0);
        acc0a = __builtin_amdgcn_mfma_f32_32x32x16_bf16(a2[0][1], hbf[1], acc0a, 0, 0, 0);
        acc1a = __builtin_amdgcn_mfma_f32_32x32x16_bf16(a2[1][1], hbf[1], acc1a, 0, 0, 0);
        acc0b = __builtin_amdgcn_mfma_f32_32x32x16_bf16(a2[0][3], hbf[3], acc0b, 0, 0, 0);
        acc1b = __builtin_amdgcn_mfma_f32_32x32x16_bf16(a2[1][3], hbf[3], acc1b, 0, 0, 0);
        __builtin_amdgcn_s_setprio(0);

        // Off-chain: next step's delta-independent L1 (software pipeline).
        {
            uint4 xu;
            xu.x = pack2_bf16(nf0, nf1);
            xu.y = pack2_bf16(nf2, 0.f);
            xu.z = 0x3F80u; xu.w = 0u;
            const bf16x8 xb = __builtin_bit_cast(bf16x8, xu);
            Pn0 = __builtin_amdgcn_mfma_f32_32x32x16_bf16(a1[0], xb, zc, 0, 0, 0);
            Pn1 = __builtin_amdgcn_mfma_f32_32x32x16_bf16(a1[1], xb, zc, 0, 0, 0);
        }

        // Merge the split chains (packed f32 adds, depth 1).
        acc0 = acc0a + acc0b;
        acc1 = acc1a + acc1b;

        // L3 dot: packed-f32, R12-proven chains/order.
        f32x2 p01 = z2, p23 = z2;
#pragma unroll
        for (int q = 0; q < 4; ++q) {
            f32x2 a0lo = { acc0[4*q+0], acc0[4*q+1] };
            f32x2 a0hi = { acc0[4*q+2], acc0[4*q+3] };
            f32x2 a1lo = { acc1[4*q+0], acc1[4*q+1] };
            f32x2 a1hi = { acc1[4*q+2], acc1[4*q+3] };
            p01 = __builtin_elementwise_fma(__builtin_elementwise_max(a0lo, z2), w3f[0][2*q+0], p01);
            p23 = __builtin_elementwise_fma(__builtin_elementwise_max(a0hi, z2), w3f[0][2*q+1], p23);
            p01 = __builtin_elementwise_fma(__builtin_elementwise_max(a1lo, z2), w3f[1][2*q+0], p01);
            p23 = __builtin_elementwise_fma(__builtin_elementwise_max(a1hi, z2), w3f[1][2*q+1], p23);
        }
        float p = (p01[0] + p01[1]) + (p23[0] + p23[1]);
        p += __shfl_xor(p, 32, 64);   // cross-half sum (proven; see hazard note)
        delta = p + b3v;

        if (half == 0) dl[col*61 + t] = delta;
    };

    // Ping-pong P buffers: no register copies between steps.
#pragma unroll 1
    for (int t = 0; t < TSTEPS; t += 2) {
        stepfn(t,     PA0, PA1, PB0, PB1);
        stepfn(t + 1, PB0, PB1, PA0, PA1);
    }

    // Coalesced flush: out[nbase*60 + i], i = col*60 + t ; LDS idx = i + i/60.
    float* ob = out + (size_t)nbase * TSTEPS;
#pragma unroll 1
    for (int i = lane; i < 32 * TSTEPS; i += 64) {
        const int cc = i / TSTEPS;
        ob[i] = dl[i + cc];
    }
}

extern "C" void kernel_launch(void* const* d_in, const int* in_sizes, int n_in,
                              void* d_out, int out_size, void* d_ws, size_t ws_size,
                              hipStream_t stream) {
    const float* feat = (const float*)d_in[0];
    const float* W1   = (const float*)d_in[1];
    const float* b1   = (const float*)d_in[2];
    const float* W2   = (const float*)d_in[3];
    const float* b2   = (const float*)d_in[4];
    const float* W3   = (const float*)d_in[5];
    const float* b3   = (const float*)d_in[6];
    float* out = (float*)d_out;

    const int N = in_sizes[0] / (TSTEPS * 3);
    const int block = 256;                  // 4 waves x 32 samples = 128 samples/block
    const int grid = (N + 127) / 128;
    ffn_mfma32<<<grid, block, 0, stream>>>(feat, W1, b1, W2, b2, W3, b3, out, N);
}